// Round 5
// baseline (470.586 us; speedup 1.0000x reference)
//
#include <hip/hip_runtime.h>
#include <hip/hip_bf16.h>

// Problem: B=256, N=512, adjacency fp32 [B,N,N].
// out[b,i,j] = dinv[b,i] * a_hat[b,i,j] * dinv[b,j]
//   a_hat = adjacency with diagonal replaced by mask = (rowsum != 0)
//   deg   = rowsum - diag + mask   (entries 0/1 -> exact in fp32)
//   dinv  = deg > 0 ? 1/sqrt(deg) : 0
// Diagonal output = dinv_i * 1.0 * dinv_i (mask=0 => dinv=0).
//
// Round-4 lesson: whole-array two-pass leaves pass 2 re-fetching much of the
// 268 MB input from HBM (input ~= L3 capacity; the write stream evicts it).
// Fix: tile the two passes over 64-batch chunks (64 MB). degree(c) then
// scale(c) back-to-back => reuse distance 64 MB read + 64 MB write << 256 MB
// L3, so scale's re-read is L3-hot by construction. 8 dispatches total.

#define NN 512    // N
#define NB 256    // B
#define CB 64     // batches per chunk
#define NCHUNK (NB / CB)

typedef float f32x4 __attribute__((ext_vector_type(4)));

// Degree pass over one chunk: one 64-lane wave per row; 2 float4 loads/lane;
// butterfly-reduce rowsum + diagonal; write dinv.
__global__ __launch_bounds__(256) void degree_kernel(
    const float* __restrict__ adj, float* __restrict__ dinv, int rowOff) {
    int gtid = blockIdx.x * blockDim.x + threadIdx.x;
    int row  = rowOff + (gtid >> 6);   // global row index
    int lane = threadIdx.x & 63;

    const f32x4* r4 = (const f32x4*)(adj + (size_t)row * NN);
    f32x4 a0 = r4[lane];               // cols [lane*4, lane*4+4)
    f32x4 a1 = r4[lane + 64];          // cols [256+lane*4, ...)

    float s = (a0.x + a0.y) + (a0.z + a0.w) + (a1.x + a1.y) + (a1.z + a1.w);

    int i = row & (NN - 1);            // diagonal column (within batch)
    float diag = 0.0f;
    int j0 = lane << 2;
    if (i >= j0 && i < j0 + 4) diag = ((const float*)&a0)[i - j0];
    int j1 = 256 + (lane << 2);
    if (i >= j1 && i < j1 + 4) diag = ((const float*)&a1)[i - j1];

    #pragma unroll
    for (int off = 32; off > 0; off >>= 1) {
        s    += __shfl_xor(s, off);
        diag += __shfl_xor(diag, off);
    }

    if (lane == 0) {
        float mask = (s != 0.0f) ? 1.0f : 0.0f;
        float deg  = s - diag + mask;
        dinv[row]  = (deg > 0.0f) ? (1.0f / sqrtf(deg)) : 0.0f;
    }
}

// Scale pass over one chunk: one thread per output float4. Loads are L3-hot
// (chunk was just read by degree_kernel); stores nontemporal so the write
// stream doesn't evict the chunk's input lines from L3 mid-pass.
__global__ __launch_bounds__(256) void scale_kernel(
    const float* __restrict__ adj, const float* __restrict__ dinv,
    float* __restrict__ out, size_t idx4Off) {
    size_t idx4 = idx4Off + (size_t)blockIdx.x * blockDim.x + threadIdx.x;

    int    j4   = (int)(idx4 & 127);        // float4 column (N/4 = 128)
    size_t row  = idx4 >> 7;                // global row in [0, B*N)
    int    i    = (int)(row & (NN - 1));    // diagonal column
    size_t rowb = row & ~(size_t)(NN - 1);  // b*N

    f32x4 a  = ((const f32x4*)adj)[idx4];
    f32x4 dj = ((const f32x4*)(dinv + rowb))[j4];
    float di = dinv[row];

    int j = j4 << 2;
    // reference order: (dinv_i * a_hat) * dinv_j
    f32x4 o;
    o.x = (di * ((j + 0 == i) ? 1.0f : a.x)) * dj.x;
    o.y = (di * ((j + 1 == i) ? 1.0f : a.y)) * dj.y;
    o.z = (di * ((j + 2 == i) ? 1.0f : a.z)) * dj.z;
    o.w = (di * ((j + 3 == i) ? 1.0f : a.w)) * dj.w;

    __builtin_nontemporal_store(o, &((f32x4*)out)[idx4]);
}

extern "C" void kernel_launch(void* const* d_in, const int* in_sizes, int n_in,
                              void* d_out, int out_size, void* d_ws, size_t ws_size,
                              hipStream_t stream) {
    const float* adj = (const float*)d_in[0];
    float* out  = (float*)d_out;
    float* dinv = (float*)d_ws;            // B*N floats = 512 KiB scratch

    const int    rowsPerChunk = CB * NN;                  // 32768
    const size_t f4PerChunk   = (size_t)CB * NN * NN / 4; // 4,194,304

    for (int c = 0; c < NCHUNK; ++c) {
        degree_kernel<<<rowsPerChunk / 4, 256, 0, stream>>>(
            adj, dinv, c * rowsPerChunk);
        scale_kernel<<<(unsigned)(f4PerChunk / 256), 256, 0, stream>>>(
            adj, dinv, out, (size_t)c * f4PerChunk);
    }
}